// Round 1
// baseline (3814.989 us; speedup 1.0000x reference)
//
#include <hip/hip_runtime.h>

// Chambolle-Pock primal-dual ROF, 20 iterations, 4096x4096.
// Two kernels per iteration (dual then primal), 40 launches total.
// x_tilde lives in d_out; x and y live in d_ws (192 MB).

#define MM 4096
#define NN 4096

static constexpr float SIGMA_F  = 14.285714285714286f;  // 1/(7*0.01)
static constexpr float TAU_F    = 0.01f;
static constexpr float THETA_F  = 0.5f;
static constexpr float LT_F     = 0.07f;                // LAMBDA_ROF * TAU
static constexpr float INV_DEN  = 1.0f / 1.07f;         // 1/(1 + LAMBDA*TAU)

__device__ __forceinline__ float clip1(float v) {
    return fminf(1.0f, fmaxf(-1.0f, v));
}

// y_out = clip(y_in + SIGMA * forward_grad(xt) * w, -1, 1)
__global__ __launch_bounds__(256) void dual_kernel(
    const float* __restrict__ xt, const float* __restrict__ y_in,
    const float* __restrict__ w, float* __restrict__ y_out)
{
    const int i = blockIdx.y * blockDim.y + threadIdx.y;
    const int j = (blockIdx.x * blockDim.x + threadIdx.x) * 4;
    if (i >= MM || j >= NN) return;
    const size_t P   = (size_t)MM * NN;
    const size_t idx = (size_t)i * NN + j;

    const float4 xt4 = *(const float4*)(xt + idx);

    // forward x-gradient (last column = 0). j+3 == NN-1 only when j+4 == NN.
    float4 gx;
    gx.x = xt4.y - xt4.x;
    gx.y = xt4.z - xt4.y;
    gx.z = xt4.w - xt4.z;
    gx.w = (j + 4 < NN) ? (xt[idx + 4] - xt4.w) : 0.0f;

    // forward y-gradient (last row = 0)
    float4 gy;
    if (i < MM - 1) {
        const float4 xd = *(const float4*)(xt + idx + NN);
        gy.x = xd.x - xt4.x; gy.y = xd.y - xt4.y;
        gy.z = xd.z - xt4.z; gy.w = xd.w - xt4.w;
    } else {
        gy = make_float4(0.f, 0.f, 0.f, 0.f);
    }

    const float4 w0 = *(const float4*)(w + idx);
    const float4 w1 = *(const float4*)(w + P + idx);
    float4 ya = *(const float4*)(y_in + idx);
    float4 yb = *(const float4*)(y_in + P + idx);

    ya.x = clip1(fmaf(SIGMA_F * gx.x, w0.x, ya.x));
    ya.y = clip1(fmaf(SIGMA_F * gx.y, w0.y, ya.y));
    ya.z = clip1(fmaf(SIGMA_F * gx.z, w0.z, ya.z));
    ya.w = clip1(fmaf(SIGMA_F * gx.w, w0.w, ya.w));

    yb.x = clip1(fmaf(SIGMA_F * gy.x, w1.x, yb.x));
    yb.y = clip1(fmaf(SIGMA_F * gy.y, w1.y, yb.y));
    yb.z = clip1(fmaf(SIGMA_F * gy.z, w1.z, yb.z));
    yb.w = clip1(fmaf(SIGMA_F * gy.w, w1.w, yb.w));

    *(float4*)(y_out + idx)     = ya;
    *(float4*)(y_out + P + idx) = yb;
}

// x_new = (x + TAU*div(w*y) + LT*img) / denom ; xt = (1+THETA)*x_new - THETA*x
__global__ __launch_bounds__(256) void primal_kernel(
    const float* __restrict__ x_in, const float* __restrict__ y,
    const float* __restrict__ w, const float* __restrict__ img,
    float* __restrict__ x_out, float* __restrict__ xt_out)
{
    const int i = blockIdx.y * blockDim.y + threadIdx.y;
    const int j = (blockIdx.x * blockDim.x + threadIdx.x) * 4;
    if (i >= MM || j >= NN) return;
    const size_t P   = (size_t)MM * NN;
    const size_t idx = (size_t)i * NN + j;

    // horizontal divergence of h = w0*y0
    const float4 y0v = *(const float4*)(y + idx);
    const float4 w0v = *(const float4*)(w + idx);
    const float h0 = y0v.x * w0v.x;
    const float h1 = y0v.y * w0v.y;
    const float h2 = y0v.z * w0v.z;
    const float h3 = y0v.w * w0v.w;
    const float hm1 = (j > 0) ? (y[idx - 1] * w[idx - 1]) : 0.0f;
    // dh[jj] = (jj < NN-1 ? h[jj] : 0) - (jj > 0 ? h[jj-1] : 0)
    const float dh0 = h0 - hm1;                              // j..j+2 < NN-1 always
    const float dh1 = h1 - h0;
    const float dh2 = h2 - h1;
    const float dh3 = ((j + 3 < NN - 1) ? h3 : 0.0f) - h2;

    // vertical divergence of v = w1*y1
    float4 vi = make_float4(0.f, 0.f, 0.f, 0.f);
    if (i < MM - 1) {
        const float4 y1v = *(const float4*)(y + P + idx);
        const float4 w1v = *(const float4*)(w + P + idx);
        vi.x = y1v.x * w1v.x; vi.y = y1v.y * w1v.y;
        vi.z = y1v.z * w1v.z; vi.w = y1v.w * w1v.w;
    }
    float4 vu = make_float4(0.f, 0.f, 0.f, 0.f);
    if (i > 0) {
        const float4 y1u = *(const float4*)(y + P + idx - NN);
        const float4 w1u = *(const float4*)(w + P + idx - NN);
        vu.x = y1u.x * w1u.x; vu.y = y1u.y * w1u.y;
        vu.z = y1u.z * w1u.z; vu.w = y1u.w * w1u.w;
    }
    const float dv0 = vi.x - vu.x;
    const float dv1 = vi.y - vu.y;
    const float dv2 = vi.z - vu.z;
    const float dv3 = vi.w - vu.w;

    const float4 xv = *(const float4*)(x_in + idx);
    const float4 gv = *(const float4*)(img + idx);

    float4 xn;
    xn.x = (xv.x + TAU_F * (dh0 + dv0) + LT_F * gv.x) * INV_DEN;
    xn.y = (xv.y + TAU_F * (dh1 + dv1) + LT_F * gv.y) * INV_DEN;
    xn.z = (xv.z + TAU_F * (dh2 + dv2) + LT_F * gv.z) * INV_DEN;
    xn.w = (xv.w + TAU_F * (dh3 + dv3) + LT_F * gv.w) * INV_DEN;

    float4 xt;
    xt.x = (1.0f + THETA_F) * xn.x - THETA_F * xv.x;
    xt.y = (1.0f + THETA_F) * xn.y - THETA_F * xv.y;
    xt.z = (1.0f + THETA_F) * xn.z - THETA_F * xv.z;
    xt.w = (1.0f + THETA_F) * xn.w - THETA_F * xv.w;

    *(float4*)(x_out + idx)  = xn;
    *(float4*)(xt_out + idx) = xt;
}

extern "C" void kernel_launch(void* const* d_in, const int* in_sizes, int n_in,
                              void* d_out, int out_size, void* d_ws, size_t ws_size,
                              hipStream_t stream) {
    const float* img  = (const float*)d_in[0];   // [1,M,N]
    const float* w    = (const float*)d_in[1];   // [2,M,N]
    const float* y0in = (const float*)d_in[2];   // [2,M,N]
    float* xt_buf = (float*)d_out;               // x_tilde lives here (final output)
    float* x_buf  = (float*)d_ws;                // [M*N]
    float* y_buf  = x_buf + (size_t)MM * NN;     // [2*M*N]

    const dim3 block(64, 4);
    const dim3 grid(NN / (4 * 64), MM / 4);

    const int MAX_IT = 20;
    for (int it = 0; it < MAX_IT; ++it) {
        const float* xt_src = (it == 0) ? img  : xt_buf;
        const float* y_src  = (it == 0) ? y0in : y_buf;
        dual_kernel<<<grid, block, 0, stream>>>(xt_src, y_src, w, y_buf);

        const float* x_src = (it == 0) ? img : x_buf;
        primal_kernel<<<grid, block, 0, stream>>>(x_src, y_buf, w, img, x_buf, xt_buf);
    }
}

// Round 3
// 1752.000 us; speedup vs baseline: 2.1775x; 2.1775x over previous
//
#include <hip/hip_runtime.h>

// Chambolle-Pock primal-dual ROF, 20 iterations, 4096x4096.
// Fused dual+primal per iteration (20 launches + prep), fp16 state.
// State: x carried as (x_prev, x_cur) in a 3-buffer half rotation (xt
// recomputed on the fly as x + theta*(x - x_prev)); y ping-pongs between
// ws and d_out (half). Last iteration writes f32 x_tilde to d_out.

#define MM 4096
#define NN 4096
static constexpr size_t PP = (size_t)MM * NN;

static constexpr float SIGMA_F  = 14.285714285714286f;  // 1/(7*0.01)
static constexpr float TAU_F    = 0.01f;
static constexpr float THETA_F  = 0.5f;
static constexpr float LT_F     = 0.07f;                // LAMBDA_ROF * TAU
static constexpr float INV_DEN  = 1.0f / 1.07f;

typedef _Float16 h16;
typedef __attribute__((ext_vector_type(8))) _Float16 h16x8;
typedef __attribute__((ext_vector_type(4))) float f32x4;

__device__ __forceinline__ float clip1(float v) {
    return fminf(1.0f, fmaxf(-1.0f, v));
}

template<bool H>
__device__ __forceinline__ void ld8(const void* p, size_t idx, float* o) {
    if constexpr (H) {
        h16x8 v = *reinterpret_cast<const h16x8*>(reinterpret_cast<const h16*>(p) + idx);
        for (int e = 0; e < 8; ++e) o[e] = (float)v[e];
    } else {
        const float* q = reinterpret_cast<const float*>(p) + idx;
        f32x4 a = *reinterpret_cast<const f32x4*>(q);
        f32x4 b = *reinterpret_cast<const f32x4*>(q + 4);
        o[0]=a.x; o[1]=a.y; o[2]=a.z; o[3]=a.w;
        o[4]=b.x; o[5]=b.y; o[6]=b.z; o[7]=b.w;
    }
}
template<bool H>
__device__ __forceinline__ float ld1(const void* p, size_t idx) {
    if constexpr (H) return (float)reinterpret_cast<const h16*>(p)[idx];
    else             return reinterpret_cast<const float*>(p)[idx];
}

// XM: 0 = xprev,xcur both f32 (img); 1 = xprev f32, xcur half; 2 = both half.
template<int XM, bool LAST, bool WH>
__global__ __launch_bounds__(256)
void fused_kernel(const void* __restrict__ xprev, const void* __restrict__ xcur,
                  const h16* __restrict__ yin, const void* __restrict__ w,
                  const float* __restrict__ img,
                  h16* __restrict__ xnext, h16* __restrict__ yout,
                  float* __restrict__ out)
{
    constexpr bool HP = (XM == 2);
    constexpr bool HC = (XM >= 1);
    const int i  = blockIdx.y * 4 + threadIdx.y;
    const int j0 = (blockIdx.x * 64 + threadIdx.x) * 8;
    const size_t idx = (size_t)i * NN + j0;
    const bool hasL = (j0 > 0);
    const bool hasR = (j0 + 8 < NN);
    const bool hasU = (i > 0);
    const bool hasD = (i < MM - 1);

    // ---- x_tilde reconstruction: xt = xc + THETA*(xc - xp) ----
    float xpC[8], xcC[8], xtC[8];
    ld8<HP>(xprev, idx, xpC);
    ld8<HC>(xcur,  idx, xcC);
    for (int e = 0; e < 8; ++e) xtC[e] = fmaf(THETA_F, xcC[e] - xpC[e], xcC[e]);

    float xtL = 0.f, xtR = 0.f;
    if (hasL) { float xp = ld1<HP>(xprev, idx-1), xc = ld1<HC>(xcur, idx-1);
                xtL = fmaf(THETA_F, xc - xp, xc); }
    if (hasR) { float xp = ld1<HP>(xprev, idx+8), xc = ld1<HC>(xcur, idx+8);
                xtR = fmaf(THETA_F, xc - xp, xc); }

    float xtU[8], xtD[8];
    if (hasU) {
        float xp[8], xc[8];
        ld8<HP>(xprev, idx - NN, xp);
        ld8<HC>(xcur,  idx - NN, xc);
        for (int e = 0; e < 8; ++e) xtU[e] = fmaf(THETA_F, xc[e] - xp[e], xc[e]);
    } else {
        for (int e = 0; e < 8; ++e) xtU[e] = 0.f;
    }
    if (hasD) {
        float xp[8], xc[8];
        ld8<HP>(xprev, idx + NN, xp);
        ld8<HC>(xcur,  idx + NN, xc);
        for (int e = 0; e < 8; ++e) xtD[e] = fmaf(THETA_F, xc[e] - xp[e], xc[e]);
    } else {
        for (int e = 0; e < 8; ++e) xtD[e] = 0.f;
    }

    // ---- y_prev loads (half) ----
    float y0C[8], y1C[8], y1U[8];
    ld8<true>(yin, idx, y0C);
    ld8<true>(yin, PP + idx, y1C);
    float y0L = hasL ? ld1<true>(yin, idx - 1) : 0.f;
    if (hasU) {
        ld8<true>(yin, PP + idx - NN, y1U);
    } else {
        for (int e = 0; e < 8; ++e) y1U[e] = 0.f;
    }

    // ---- w loads ----
    float w0C[8], w1C[8], w1U[8];
    ld8<WH>(w, idx, w0C);
    ld8<WH>(w, PP + idx, w1C);
    float w0L = hasL ? ld1<WH>(w, idx - 1) : 0.f;
    if (hasU) {
        ld8<WH>(w, PP + idx - NN, w1U);
    } else {
        for (int e = 0; e < 8; ++e) w1U[e] = 0.f;
    }

    float gv[8];
    ld8<false>(img, idx, gv);

    // ---- dual update (recomputed incl. left/up halo) ----
    float y0n[8];
    for (int e = 0; e < 7; ++e)
        y0n[e] = clip1(fmaf(SIGMA_F * (xtC[e+1] - xtC[e]), w0C[e], y0C[e]));
    { float gx7 = hasR ? (xtR - xtC[7]) : 0.f;
      y0n[7] = clip1(fmaf(SIGMA_F * gx7, w0C[7], y0C[7])); }
    float y0nL = hasL ? clip1(fmaf(SIGMA_F * (xtC[0] - xtL), w0L, y0L)) : 0.f;

    float y1nC[8], y1nU[8];
    for (int e = 0; e < 8; ++e) {
        float gy = hasD ? (xtD[e] - xtC[e]) : 0.f;
        y1nC[e] = clip1(fmaf(SIGMA_F * gy, w1C[e], y1C[e]));
    }
    if (hasU) {
        for (int e = 0; e < 8; ++e)
            y1nU[e] = clip1(fmaf(SIGMA_F * (xtC[e] - xtU[e]), w1U[e], y1U[e]));
    } else {
        for (int e = 0; e < 8; ++e) y1nU[e] = 0.f;
    }

    // ---- weighted divergence ----
    float h[8];
    for (int e = 0; e < 8; ++e) h[e] = w0C[e] * y0n[e];
    const float hL = hasL ? w0L * y0nL : 0.f;
    float dh[8];
    dh[0] = h[0] - hL;
    for (int e = 1; e < 7; ++e) dh[e] = h[e] - h[e-1];
    dh[7] = (hasR ? h[7] : 0.f) - h[6];

    float dv[8];
    for (int e = 0; e < 8; ++e)
        dv[e] = (hasD ? w1C[e] * y1nC[e] : 0.f) - (hasU ? w1U[e] * y1nU[e] : 0.f);

    // ---- primal update ----
    float xn[8];
    for (int e = 0; e < 8; ++e)
        xn[e] = (xcC[e] + TAU_F * (dh[e] + dv[e]) + LT_F * gv[e]) * INV_DEN;

    if constexpr (!LAST) {
        h16x8 s0, s1, sx;
        for (int e = 0; e < 8; ++e) {
            s0[e] = (h16)y0n[e];
            s1[e] = (h16)y1nC[e];
            sx[e] = (h16)xn[e];
        }
        *reinterpret_cast<h16x8*>(yout + idx)      = s0;
        *reinterpret_cast<h16x8*>(yout + PP + idx) = s1;
        *reinterpret_cast<h16x8*>(xnext + idx)     = sx;
    } else {
        float xt_[8];
        for (int e = 0; e < 8; ++e) xt_[e] = fmaf(THETA_F, xn[e] - xcC[e], xn[e]);
        f32x4 a, b;
        a.x = xt_[0]; a.y = xt_[1]; a.z = xt_[2]; a.w = xt_[3];
        b.x = xt_[4]; b.y = xt_[5]; b.z = xt_[6]; b.w = xt_[7];
        *reinterpret_cast<f32x4*>(out + idx)     = a;
        *reinterpret_cast<f32x4*>(out + idx + 4) = b;
    }
}

__global__ __launch_bounds__(256)
void cvt_f32_h16(const float* __restrict__ src, h16* __restrict__ dst) {
    const size_t t = (size_t)blockIdx.x * blockDim.x + threadIdx.x;
    const size_t idx = t * 8;
    f32x4 a = *reinterpret_cast<const f32x4*>(src + idx);
    f32x4 b = *reinterpret_cast<const f32x4*>(src + idx + 4);
    h16x8 v;
    v[0]=(h16)a.x; v[1]=(h16)a.y; v[2]=(h16)a.z; v[3]=(h16)a.w;
    v[4]=(h16)b.x; v[5]=(h16)b.y; v[6]=(h16)b.z; v[7]=(h16)b.w;
    *reinterpret_cast<h16x8*>(dst + idx) = v;
}

template<int XM, bool LAST>
static void launch_one(bool wh, dim3 g, dim3 b, hipStream_t s,
                       const void* xp, const void* xc, const h16* yin, const void* w,
                       const float* img, h16* xn, h16* yo, float* out) {
    if (wh) fused_kernel<XM, LAST, true ><<<g, b, 0, s>>>(xp, xc, yin, w, img, xn, yo, out);
    else    fused_kernel<XM, LAST, false><<<g, b, 0, s>>>(xp, xc, yin, w, img, xn, yo, out);
}

extern "C" void kernel_launch(void* const* d_in, const int* in_sizes, int n_in,
                              void* d_out, int out_size, void* d_ws, size_t ws_size,
                              hipStream_t stream) {
    const float* img = (const float*)d_in[0];   // [1,M,N]
    const float* w   = (const float*)d_in[1];   // [2,M,N]
    const float* y0  = (const float*)d_in[2];   // [2,M,N]

    h16* base = (h16*)d_ws;
    h16* xb[3] = { base, base + PP, base + 2 * PP };
    h16* yA  = base + 3 * PP;            // 2 planes
    h16* w_h = base + 5 * PP;            // 2 planes (optional)
    h16* yB  = (h16*)d_out;              // 2 half planes == out_size f32 bytes

    const bool use_wh = (ws_size >= 7 * PP * sizeof(h16));

    // prep: y0 -> half (into yB = d_out); optionally w -> half
    {
        const int blocks = (int)(2 * PP / (8 * 256));
        cvt_f32_h16<<<blocks, 256, 0, stream>>>(y0, yB);
        if (use_wh) cvt_f32_h16<<<blocks, 256, 0, stream>>>(w, w_h);
    }
    const void* wp = use_wh ? (const void*)w_h : (const void*)w;

    const dim3 block(64, 4);
    const dim3 grid(NN / (64 * 8), MM / 4);
    const int MAX_IT = 20;

    for (int t = 0; t < MAX_IT; ++t) {
        const void* xp = (t <= 1) ? (const void*)img : (const void*)xb[(t - 2) % 3];
        const void* xc = (t == 0) ? (const void*)img : (const void*)xb[(t - 1) % 3];
        const h16* yin = (t % 2 == 0) ? yB : yA;
        h16* yout      = (t % 2 == 0) ? yA : yB;
        h16* xnext     = xb[t % 3];
        const bool last = (t == MAX_IT - 1);

        if (t == 0)
            launch_one<0, false>(use_wh, grid, block, stream, xp, xc, yin, wp, img, xnext, yout, (float*)d_out);
        else if (t == 1)
            launch_one<1, false>(use_wh, grid, block, stream, xp, xc, yin, wp, img, xnext, yout, (float*)d_out);
        else if (!last)
            launch_one<2, false>(use_wh, grid, block, stream, xp, xc, yin, wp, img, xnext, yout, (float*)d_out);
        else
            launch_one<2, true >(use_wh, grid, block, stream, xp, xc, yin, wp, img, xnext, yout, (float*)d_out);
    }
}